// Round 1
// baseline (2543.724 us; speedup 1.0000x reference)
//
#include <hip/hip_runtime.h>

#define B_   32
#define L_   1024
#define CD_  256
#define ZD_  256
#define P_   12
#define NEG_ 8
#define NS_  9     // 1 positive + 8 negatives
#define TL_  32    // l-rows per block

// ws layout: ws[0] = loss accumulator, ws[1] = msum
__global__ void cnce_init(const int* __restrict__ length, float* ws) {
    int t = threadIdx.x;
    int v = (t < B_) ? length[t] : 0;
    #pragma unroll
    for (int m = 1; m < 64; m <<= 1) v += __shfl_xor(v, m);
    if (t == 0) { ws[0] = 0.f; ws[1] = (float)v; }
}

__global__ __launch_bounds__(256) void cnce_main(
        const float* __restrict__ c, const float* __restrict__ z,
        const float* __restrict__ W, const int* __restrict__ neg_shift,
        const int* __restrict__ length, float* __restrict__ ws) {
    const int p  = blockIdx.z;
    const int b  = blockIdx.y;
    const int l0 = blockIdx.x * TL_;
    const int tid  = threadIdx.x;
    const int w    = tid >> 6;
    const int lane = tid & 63;
    const int d    = tid;            // 256 threads cover ZD exactly

    __shared__ float cs[TL_][CD_];
    __shared__ float red[4][NS_][TL_];
    __shared__ float sc[NS_][TL_];
    __shared__ int   sh[NS_];

    if (tid < NS_) sh[tid] = (tid == 0) ? (p + 1) : neg_shift[tid - 1];

    // stage c tile (contiguous 32KB)
    {
        const float4* src = (const float4*)(c + (size_t)(b * L_ + l0) * CD_);
        float4* dst = (float4*)&cs[0][0];
        #pragma unroll
        for (int i = 0; i < (TL_ * CD_ / 4) / 256; ++i)
            dst[tid + i * 256] = src[tid + i * 256];
    }
    __syncthreads();

    // ---- Phase A: Wc[l][d] for this thread's d, all 32 l ----
    float acc[TL_];
    #pragma unroll
    for (int l = 0; l < TL_; ++l) acc[l] = 0.f;

    const float* Wp = W + (size_t)p * CD_ * ZD_ + d;
    for (int cc = 0; cc < CD_; cc += 4) {
        float w0 = Wp[(size_t)(cc + 0) * ZD_];
        float w1 = Wp[(size_t)(cc + 1) * ZD_];
        float w2 = Wp[(size_t)(cc + 2) * ZD_];
        float w3 = Wp[(size_t)(cc + 3) * ZD_];
        #pragma unroll
        for (int l = 0; l < TL_; ++l) {
            float4 cv = *(const float4*)&cs[l][cc];
            acc[l] = fmaf(cv.x, w0, acc[l]);
            acc[l] = fmaf(cv.y, w1, acc[l]);
            acc[l] = fmaf(cv.z, w2, acc[l]);
            acc[l] = fmaf(cv.w, w3, acc[l]);
        }
    }

    // ---- Phase B: scores for 9 shifts ----
    const float* zb = z + (size_t)b * L_ * ZD_;
    for (int j = 0; j < NS_; ++j) {
        const int s = sh[j];
        for (int l = 0; l < TL_; ++l) {
            const int row = (l0 + l + s) & (L_ - 1);
            float part = acc[l] * zb[(size_t)row * ZD_ + d];
            #pragma unroll
            for (int m = 1; m < 64; m <<= 1) part += __shfl_xor(part, m);
            if (lane == 0) red[w][j][l] = part;
        }
    }
    __syncthreads();

    for (int i = tid; i < NS_ * TL_; i += 256) {
        int j = i / TL_, l = i % TL_;
        sc[j][l] = red[0][j][l] + red[1][j][l] + red[2][j][l] + red[3][j][l];
    }
    __syncthreads();

    // ---- logsumexp + masked accumulate ----
    float blockSum = 0.f;
    if (tid < TL_) {
        const int l = tid;
        float m = sc[0][l];
        #pragma unroll
        for (int j = 1; j < NS_; ++j) m = fmaxf(m, sc[j][l]);
        float se = 0.f;
        #pragma unroll
        for (int j = 0; j < NS_; ++j) se += __expf(sc[j][l] - m);
        float loss = __logf(se) + m - sc[0][l];
        if (l0 + l < length[b]) blockSum = loss;
    }
    if (tid < 64) {
        #pragma unroll
        for (int m = 1; m < 32; m <<= 1) blockSum += __shfl_xor(blockSum, m);
        if (tid == 0) atomicAdd(&ws[0], blockSum);
    }
}

__global__ void cnce_fin(const float* __restrict__ ws, float* __restrict__ out) {
    out[0] = ws[0] / ws[1];
}

extern "C" void kernel_launch(void* const* d_in, const int* in_sizes, int n_in,
                              void* d_out, int out_size, void* d_ws, size_t ws_size,
                              hipStream_t stream) {
    const float* c  = (const float*)d_in[0];
    const float* z  = (const float*)d_in[1];
    const float* W  = (const float*)d_in[2];
    const int* neg_shift = (const int*)d_in[3];
    const int* length    = (const int*)d_in[4];
    float* out = (float*)d_out;
    float* ws  = (float*)d_ws;

    cnce_init<<<1, 64, 0, stream>>>(length, ws);
    dim3 grid(L_ / TL_, B_, P_);
    cnce_main<<<grid, 256, 0, stream>>>(c, z, W, neg_shift, length, ws);
    cnce_fin<<<1, 1, 0, stream>>>(ws, out);
}

// Round 3
// 602.766 us; speedup vs baseline: 4.2201x; 4.2201x over previous
//
#include <hip/hip_runtime.h>

#define B_   32
#define L_   1024
#define CD_  256
#define ZD_  256
#define P_   12
#define NS_  9     // 1 positive + 8 negatives
#define TL_  64    // l-rows per block

typedef __attribute__((ext_vector_type(8))) short bf16x8;
typedef __attribute__((ext_vector_type(4))) float f32x4;

__device__ __forceinline__ unsigned short f2b(float f) {
    unsigned u = __float_as_uint(f);
    u += 0x7FFFu + ((u >> 16) & 1u);          // round-nearest-even
    return (unsigned short)(u >> 16);
}

// ws layout: ws[0] = loss accumulator, ws[1] = msum; WT bf16 at byte offset 256
__global__ void cnce_init(const int* __restrict__ length, float* ws) {
    int t = threadIdx.x;
    int v = (t < B_) ? length[t] : 0;
    #pragma unroll
    for (int m = 1; m < 64; m <<= 1) v += __shfl_xor(v, m);
    if (t == 0) { ws[0] = 0.f; ws[1] = (float)v; }
}

// W[p][cc][d] f32  ->  WT[p][d][cc] bf16   (coalesced reads, 16B writes)
__global__ __launch_bounds__(256) void cnce_wtk(const float* __restrict__ W,
                                                unsigned short* __restrict__ WT) {
    const int g = blockIdx.x;            // cc-group: cc0 = 8g
    const int p = blockIdx.y;
    const int d = threadIdx.x;           // 0..255
    const int cc0 = g * 8;
    const float* src = W + (size_t)p * CD_ * ZD_ + (size_t)cc0 * ZD_ + d;
    unsigned short h[8];
    #pragma unroll
    for (int i = 0; i < 8; ++i) h[i] = f2b(src[(size_t)i * ZD_]);
    unsigned short* dst = WT + ((size_t)(p * ZD_ + d)) * CD_ + cc0;
    *(int4*)dst = *(const int4*)h;
}

__global__ __launch_bounds__(256) void cnce_main(
        const float* __restrict__ c, const float* __restrict__ z,
        const unsigned short* __restrict__ WT, const int* __restrict__ neg_shift,
        const int* __restrict__ length, float* __restrict__ ws) {
    const int p  = blockIdx.z;
    const int b  = blockIdx.y;
    const int l0 = blockIdx.x * TL_;
    const int tid  = threadIdx.x;
    const int w    = tid >> 6;
    const int lane = tid & 63;

    // region 0: A-tile  64 rows x 256 k bf16 (swizzled)          = 32768 B
    // region 1: B-chunk 256 d x 64 cc bf16 (swizzled)            = 32768 B
    // after GEMM both are overwritten by Wc f32 [64][256]        = 65536 B
    __shared__ char smem[65536];
    __shared__ float sc[NS_][TL_];
    __shared__ int   sh[NS_];
    char* smemB = smem + 32768;

    if (tid < NS_) sh[tid] = (tid == 0) ? (p + 1) : neg_shift[tid - 1];

    // ---- stage A-tile: c fp32 -> bf16, swizzled ----
    {
        const float4* csrc = (const float4*)(c + (size_t)(b * L_ + l0) * CD_);
        #pragma unroll
        for (int it = 0; it < 16; ++it) {
            int fi = tid + it * 256;              // 0..4095
            int l  = fi >> 6;
            int k4 = fi & 63;                     // float4 index in row
            float4 v = csrc[fi];
            unsigned short h[4] = { f2b(v.x), f2b(v.y), f2b(v.z), f2b(v.w) };
            int byte = (l * 512 + k4 * 8) ^ ((l & 15) << 4);
            *(uint2*)(smem + byte) = *(const uint2*)h;
        }
    }

    // ---- GEMM: acc[mi][ni] over K=256 in 4 chunks of 64 ----
    f32x4 acc[4][4] = {};
    const unsigned short* WTp = WT + (size_t)p * ZD_ * CD_;
    for (int kc = 0; kc < 4; ++kc) {
        const int cc0 = kc * 64;
        #pragma unroll
        for (int it = 0; it < 8; ++it) {
            int idx = tid + it * 256;             // 0..2047
            int d = idx >> 3, q = idx & 7;
            int4 v = *(const int4*)(WTp + (size_t)d * CD_ + cc0 + q * 8);
            int byte = (d * 128 + q * 16) ^ ((d & 7) << 4);
            *(int4*)(smemB + byte) = v;
        }
        __syncthreads();
        #pragma unroll
        for (int kk = 0; kk < 2; ++kk) {
            bf16x8 av[4], bv[4];
            #pragma unroll
            for (int mi = 0; mi < 4; ++mi) {
                int l  = mi * 16 + (lane & 15);
                int k0 = kc * 64 + kk * 32 + ((lane >> 4) << 3);
                int byte = (l * 512 + k0 * 2) ^ ((l & 15) << 4);
                av[mi] = *(const bf16x8*)(smem + byte);
            }
            #pragma unroll
            for (int ni = 0; ni < 4; ++ni) {
                int d   = w * 64 + ni * 16 + (lane & 15);
                int ccL = kk * 32 + ((lane >> 4) << 3);
                int byte = (d * 128 + ccL * 2) ^ ((d & 7) << 4);
                bv[ni] = *(const bf16x8*)(smemB + byte);
            }
            #pragma unroll
            for (int mi = 0; mi < 4; ++mi)
                #pragma unroll
                for (int ni = 0; ni < 4; ++ni)
                    acc[mi][ni] = __builtin_amdgcn_mfma_f32_16x16x32_bf16(
                        av[mi], bv[ni], acc[mi][ni], 0, 0, 0);
        }
        __syncthreads();
    }

    // ---- spill Wc to LDS (C-layout: col=lane&15, row=(lane>>4)*4+reg) ----
    float* WcL = (float*)smem;                    // [64][256]
    #pragma unroll
    for (int mi = 0; mi < 4; ++mi)
        #pragma unroll
        for (int ni = 0; ni < 4; ++ni) {
            int row = mi * 16 + ((lane >> 4) << 2);
            int col = w * 64 + ni * 16 + (lane & 15);
            #pragma unroll
            for (int r = 0; r < 4; ++r)
                WcL[(row + r) * 256 + col] = acc[mi][ni][r];
        }
    __syncthreads();

    // ---- phase B: scores via 16-lane-group dot products ----
    const float* zb = z + (size_t)b * L_ * ZD_;
    const int g  = lane >> 4;                     // 4 row-groups per wave
    const int li = lane & 15;                     // 16 d-owners, 16 d each
    const int d0 = li * 16;
    for (int j = 0; j < NS_; ++j) {
        const int s = sh[j];
        #pragma unroll
        for (int rr = 0; rr < 4; ++rr) {
            const int l = w * 16 + rr * 4 + g;
            const int zrow = (l0 + l + s) & (L_ - 1);
            const float4* wp = (const float4*)(WcL + l * 256 + d0);
            const float4* zp = (const float4*)(zb + (size_t)zrow * 256 + d0);
            float part = 0.f;
            #pragma unroll
            for (int q = 0; q < 4; ++q) {
                float4 a = wp[q], v = zp[q];
                part = fmaf(a.x, v.x, part); part = fmaf(a.y, v.y, part);
                part = fmaf(a.z, v.z, part); part = fmaf(a.w, v.w, part);
            }
            #pragma unroll
            for (int m = 1; m < 16; m <<= 1) part += __shfl_xor(part, m);
            if (li == 0) sc[j][l] = part;
        }
    }
    __syncthreads();

    // ---- logsumexp + masked accumulate (wave 0) ----
    if (tid < 64) {
        const int l = tid;
        float mx = sc[0][l];
        #pragma unroll
        for (int j = 1; j < NS_; ++j) mx = fmaxf(mx, sc[j][l]);
        float se = 0.f;
        #pragma unroll
        for (int j = 0; j < NS_; ++j) se += __expf(sc[j][l] - mx);
        float loss = __logf(se) + mx - sc[0][l];
        float v = (l0 + l < length[b]) ? loss : 0.f;
        #pragma unroll
        for (int m = 1; m < 64; m <<= 1) v += __shfl_xor(v, m);
        if (tid == 0) atomicAdd(&ws[0], v);
    }
}

__global__ void cnce_fin(const float* __restrict__ ws, float* __restrict__ out) {
    out[0] = ws[0] / ws[1];
}

extern "C" void kernel_launch(void* const* d_in, const int* in_sizes, int n_in,
                              void* d_out, int out_size, void* d_ws, size_t ws_size,
                              hipStream_t stream) {
    const float* c  = (const float*)d_in[0];
    const float* z  = (const float*)d_in[1];
    const float* W  = (const float*)d_in[2];
    const int* neg_shift = (const int*)d_in[3];
    const int* length    = (const int*)d_in[4];
    float* out = (float*)d_out;
    float* ws  = (float*)d_ws;
    unsigned short* WT = (unsigned short*)((char*)d_ws + 256);

    cnce_init<<<1, 64, 0, stream>>>(length, ws);
    cnce_wtk<<<dim3(32, 12), 256, 0, stream>>>(W, WT);
    dim3 grid(L_ / TL_, B_, P_);
    cnce_main<<<grid, 256, 0, stream>>>(c, z, WT, neg_shift, length, ws);
    cnce_fin<<<1, 1, 0, stream>>>(ws, out);
}

// Round 4
// 494.104 us; speedup vs baseline: 5.1482x; 1.2199x over previous
//
#include <hip/hip_runtime.h>

#define B_   32
#define L_   1024
#define CD_  256
#define ZD_  256
#define P_   12
#define NS_  9     // 1 positive + 8 negatives
#define TL_  64    // l-rows per block

typedef __attribute__((ext_vector_type(8))) short bf16x8;
typedef __attribute__((ext_vector_type(4))) float f32x4;

__device__ __forceinline__ unsigned short f2b(float f) {
    unsigned u = __float_as_uint(f);
    u += 0x7FFFu + ((u >> 16) & 1u);          // round-nearest-even
    return (unsigned short)(u >> 16);
}

// ws layout: ws[0]=loss acc, ws[1]=msum; WT bf16 @ byte 256; zbf bf16 @ byte 1573120
__global__ void cnce_init(const int* __restrict__ length, float* ws) {
    int t = threadIdx.x;
    int v = (t < B_) ? length[t] : 0;
    #pragma unroll
    for (int m = 1; m < 64; m <<= 1) v += __shfl_xor(v, m);
    if (t == 0) { ws[0] = 0.f; ws[1] = (float)v; }
}

// W[p][cc][d] f32 -> WT[p][d][cc] bf16
__global__ __launch_bounds__(256) void cnce_wtk(const float* __restrict__ W,
                                                unsigned short* __restrict__ WT) {
    const int g = blockIdx.x;
    const int p = blockIdx.y;
    const int d = threadIdx.x;
    const int cc0 = g * 8;
    const float* src = W + (size_t)p * CD_ * ZD_ + (size_t)cc0 * ZD_ + d;
    unsigned short h[8];
    #pragma unroll
    for (int i = 0; i < 8; ++i) h[i] = f2b(src[(size_t)i * ZD_]);
    unsigned short* dst = WT + ((size_t)(p * ZD_ + d)) * CD_ + cc0;
    *(int4*)dst = *(const int4*)h;
}

// z f32 -> zbf bf16 (flat)
__global__ __launch_bounds__(256) void cnce_zprep(const float* __restrict__ z,
                                                  unsigned short* __restrict__ zbf) {
    size_t i = ((size_t)blockIdx.x * 256 + threadIdx.x) * 8;
    float4 a = *(const float4*)(z + i), b = *(const float4*)(z + i + 4);
    unsigned short h[8] = { f2b(a.x), f2b(a.y), f2b(a.z), f2b(a.w),
                            f2b(b.x), f2b(b.y), f2b(b.z), f2b(b.w) };
    *(int4*)(zbf + i) = *(const int4*)h;
}

__global__ __launch_bounds__(256, 2) void cnce_main(
        const float* __restrict__ c, const float* __restrict__ z,
        const unsigned short* __restrict__ WT,
        const unsigned short* __restrict__ zbf,   // may be null (ws too small)
        const int* __restrict__ neg_shift,
        const int* __restrict__ length, float* __restrict__ ws) {
    // XCD swizzle: hw-block h -> work; XCD k gets 4 consecutive b (zbf slice L2-fits)
    const int h = blockIdx.x;
    const int work = ((h & 7) << 6) | (h >> 3);
    const int b  = work >> 4;
    const int l0 = (work & 15) * TL_;
    const int tid  = threadIdx.x;
    const int w    = tid >> 6;
    const int lane = tid & 63;
    const int hi   = lane >> 4;
    const int m    = lane & 15;

    // [0,32768): c-tile bf16 [64][256] swizzled
    // [32768,65536): Wc bf16 [64 l][256 d] swizzled (row-major, l-major)
    __shared__ char smem[65536];
    char* wcb = smem + 32768;

    // ---- stage c tile once ----
    {
        const float4* csrc = (const float4*)(c + (size_t)(b * L_ + l0) * CD_);
        #pragma unroll
        for (int it = 0; it < 16; ++it) {
            int fi = tid + it * 256;
            int l  = fi >> 6;
            int k4 = fi & 63;
            float4 v = csrc[fi];
            unsigned short hh[4] = { f2b(v.x), f2b(v.y), f2b(v.z), f2b(v.w) };
            int byte = (l * 512 + k4 * 8) ^ ((l & 15) << 4);
            *(uint2*)(smem + byte) = *(const uint2*)hh;
        }
    }
    __syncthreads();

    // ---- hold c-fragments (MFMA B-operand) in registers across all p ----
    bf16x8 cf[8][4];
    #pragma unroll
    for (int kk = 0; kk < 8; ++kk)
        #pragma unroll
        for (int ni = 0; ni < 4; ++ni) {
            int l  = ni * 16 + m;
            int k0 = kk * 32 + hi * 8;
            int byte = (l * 512 + k0 * 2) ^ ((l & 15) << 4);
            cf[kk][ni] = *(const bf16x8*)(smem + byte);
        }

    const int len_b = length[b];
    const bool owner = (hi == (m >> 2));      // diag owner: lane=(n>>2)*16+n, reg n&3
    const int  rsel  = m & 3;
    const int  gl    = l0 + w * 16 + m;
    const bool contrib = owner && (gl < len_b);
    int s_arr[NS_ - 1];
    #pragma unroll
    for (int j = 0; j < NS_ - 1; ++j) s_arr[j] = neg_shift[j];

    const unsigned short* zbb = zbf ? zbf + (size_t)b * L_ * ZD_ : nullptr;
    const float* zbF = z + (size_t)b * L_ * ZD_;

    float lsum = 0.f;

    for (int p = 0; p < P_; ++p) {
        // ---- GEMM (operand-swapped): acc[mi][ni] = WT-rows x c-rows ----
        // C'[d][l]: col = l = ni*16+(lane&15); row = d = w*64+mi*16+(lane>>4)*4+r
        f32x4 acc[4][4];
        #pragma unroll
        for (int mi = 0; mi < 4; ++mi)
            #pragma unroll
            for (int ni = 0; ni < 4; ++ni) acc[mi][ni] = (f32x4){0.f, 0.f, 0.f, 0.f};
        const unsigned short* WTp = WT + (size_t)p * ZD_ * CD_;
        #pragma unroll
        for (int kk = 0; kk < 8; ++kk) {
            bf16x8 wf[4];
            #pragma unroll
            for (int mi = 0; mi < 4; ++mi) {
                int d  = w * 64 + mi * 16 + m;
                int k0 = kk * 32 + hi * 8;
                wf[mi] = *(const bf16x8*)(WTp + (size_t)d * CD_ + k0);
            }
            #pragma unroll
            for (int mi = 0; mi < 4; ++mi)
                #pragma unroll
                for (int ni = 0; ni < 4; ++ni)
                    acc[mi][ni] = __builtin_amdgcn_mfma_f32_16x16x32_bf16(
                        wf[mi], cf[kk][ni], acc[mi][ni], 0, 0, 0);
        }
        __syncthreads();   // all waves done reading previous p's Wc
        // ---- spill Wc: lane holds (l fixed, 4 consecutive d) -> packed b64 ----
        #pragma unroll
        for (int mi = 0; mi < 4; ++mi)
            #pragma unroll
            for (int ni = 0; ni < 4; ++ni) {
                int l  = ni * 16 + m;
                int d0 = w * 64 + mi * 16 + hi * 4;
                unsigned short hh[4] = { f2b(acc[mi][ni][0]), f2b(acc[mi][ni][1]),
                                         f2b(acc[mi][ni][2]), f2b(acc[mi][ni][3]) };
                int byte = (l * 512 + d0 * 2) ^ ((l & 15) << 4);
                *(uint2*)(wcb + byte) = *(const uint2*)hh;
            }
        __syncthreads();
        // ---- phase B: diag-MFMA scores; wave w owns rows [w*16, w*16+16) ----
        bf16x8 pav[8];
        #pragma unroll
        for (int kk = 0; kk < 8; ++kk) {
            int l  = w * 16 + m;
            int k0 = kk * 32 + hi * 8;
            int byte = (l * 512 + k0 * 2) ^ ((l & 15) << 4);
            pav[kk] = *(const bf16x8*)(wcb + byte);
        }
        float scores[NS_];
        #pragma unroll
        for (int j = 0; j < NS_; ++j) {
            const int s = (j == 0) ? (p + 1) : s_arr[j - 1];
            const int rowz = (l0 + w * 16 + m + s) & (L_ - 1);
            f32x4 e = {0.f, 0.f, 0.f, 0.f}, o = {0.f, 0.f, 0.f, 0.f};
            if (zbb) {
                const unsigned short* zr = zbb + (size_t)rowz * ZD_ + hi * 8;
                #pragma unroll
                for (int kk = 0; kk < 8; kk += 2) {
                    bf16x8 b0 = *(const bf16x8*)(zr + kk * 32);
                    bf16x8 b1 = *(const bf16x8*)(zr + kk * 32 + 32);
                    e = __builtin_amdgcn_mfma_f32_16x16x32_bf16(pav[kk],     b0, e, 0, 0, 0);
                    o = __builtin_amdgcn_mfma_f32_16x16x32_bf16(pav[kk + 1], b1, o, 0, 0, 0);
                }
            } else {
                const float* zr = zbF + (size_t)rowz * ZD_ + hi * 8;
                #pragma unroll
                for (int kk = 0; kk < 8; ++kk) {
                    float4 z0 = *(const float4*)(zr + kk * 32);
                    float4 z1 = *(const float4*)(zr + kk * 32 + 4);
                    unsigned short hh[8] = { f2b(z0.x), f2b(z0.y), f2b(z0.z), f2b(z0.w),
                                             f2b(z1.x), f2b(z1.y), f2b(z1.z), f2b(z1.w) };
                    bf16x8 bz = *(const bf16x8*)hh;
                    if (kk & 1) o = __builtin_amdgcn_mfma_f32_16x16x32_bf16(pav[kk], bz, o, 0, 0, 0);
                    else        e = __builtin_amdgcn_mfma_f32_16x16x32_bf16(pav[kk], bz, e, 0, 0, 0);
                }
            }
            scores[j] = (rsel == 0) ? e[0] + o[0] : (rsel == 1) ? e[1] + o[1]
                      : (rsel == 2) ? e[2] + o[2] : e[3] + o[3];
        }
        if (contrib) {
            float mx = scores[0];
            #pragma unroll
            for (int j = 1; j < NS_; ++j) mx = fmaxf(mx, scores[j]);
            float se = 0.f;
            #pragma unroll
            for (int j = 0; j < NS_; ++j) se += __expf(scores[j] - mx);
            lsum += __logf(se) + mx - scores[0];
        }
    }
    #pragma unroll
    for (int sh = 1; sh < 64; sh <<= 1) lsum += __shfl_xor(lsum, sh);
    if (lane == 0) atomicAdd(&ws[0], lsum);
}

__global__ void cnce_fin(const float* __restrict__ ws, float* __restrict__ out) {
    out[0] = ws[0] / ws[1];
}

extern "C" void kernel_launch(void* const* d_in, const int* in_sizes, int n_in,
                              void* d_out, int out_size, void* d_ws, size_t ws_size,
                              hipStream_t stream) {
    const float* c  = (const float*)d_in[0];
    const float* z  = (const float*)d_in[1];
    const float* W  = (const float*)d_in[2];
    const int* neg_shift = (const int*)d_in[3];
    const int* length    = (const int*)d_in[4];
    float* out = (float*)d_out;
    float* ws  = (float*)d_ws;
    unsigned short* WT = (unsigned short*)((char*)d_ws + 256);

    const size_t ZBF_OFF = 256 + (size_t)P_ * CD_ * ZD_ * 2;          // 1,573,120
    const size_t NEED    = ZBF_OFF + (size_t)B_ * L_ * ZD_ * 2;       // ~18.35 MB
    unsigned short* zbf = (ws_size >= NEED)
                        ? (unsigned short*)((char*)d_ws + ZBF_OFF) : nullptr;

    cnce_init<<<1, 64, 0, stream>>>(length, ws);
    cnce_wtk<<<dim3(32, 12), 256, 0, stream>>>(W, WT);
    if (zbf) {
        int nblk = (int)((size_t)B_ * L_ * ZD_ / (256 * 8));          // 4096
        cnce_zprep<<<nblk, 256, 0, stream>>>(z, zbf);
    }
    cnce_main<<<512, 256, 0, stream>>>(c, z, WT, zbf, neg_shift, length, ws);
    cnce_fin<<<1, 1, 0, stream>>>(ws, out);
}

// Round 5
// 397.446 us; speedup vs baseline: 6.4002x; 1.2432x over previous
//
#include <hip/hip_runtime.h>

#define B_   32
#define L_   1024
#define CD_  256
#define ZD_  256
#define P_   12
#define NS_  9     // 1 positive + 8 negatives
#define TL_  64    // l-rows per block

typedef __attribute__((ext_vector_type(8))) short bf16x8;
typedef __attribute__((ext_vector_type(4))) float f32x4;

__device__ __forceinline__ unsigned short f2b(float f) {
    unsigned u = __float_as_uint(f);
    u += 0x7FFFu + ((u >> 16) & 1u);          // round-nearest-even
    return (unsigned short)(u >> 16);
}

// ws layout: ws[0]=loss acc, ws[1]=msum; WT bf16 @ byte 256; zbf bf16 @ byte 1573120
// Fused prep: blocks [0,384): W->WT transpose; [384,4480): z->bf16; block 4480: init
__global__ __launch_bounds__(256) void cnce_prep(
        const float* __restrict__ W, unsigned short* __restrict__ WT,
        const float* __restrict__ z, unsigned short* __restrict__ zbf,
        const int* __restrict__ length, float* __restrict__ ws) {
    const int blk = blockIdx.x;
    const int tid = threadIdx.x;
    if (blk < 384) {
        const int g = blk & 31;              // cc-group: cc0 = 8g
        const int p = blk >> 5;
        const int cc0 = g * 8;
        const float* src = W + (size_t)p * CD_ * ZD_ + (size_t)cc0 * ZD_ + tid;
        unsigned short h[8];
        #pragma unroll
        for (int i = 0; i < 8; ++i) h[i] = f2b(src[(size_t)i * ZD_]);
        unsigned short* dst = WT + ((size_t)(p * ZD_ + tid)) * CD_ + cc0;
        *(int4*)dst = *(const int4*)h;
    } else if (blk < 4480) {
        if (zbf) {
            size_t i = ((size_t)(blk - 384) * 256 + tid) * 8;
            float4 a = *(const float4*)(z + i), b = *(const float4*)(z + i + 4);
            unsigned short h[8] = { f2b(a.x), f2b(a.y), f2b(a.z), f2b(a.w),
                                    f2b(b.x), f2b(b.y), f2b(b.z), f2b(b.w) };
            *(int4*)(zbf + i) = *(const int4*)h;
        }
    } else {
        if (tid < 64) {
            int v = (tid < B_) ? length[tid] : 0;
            #pragma unroll
            for (int m = 1; m < 64; m <<= 1) v += __shfl_xor(v, m);
            if (tid == 0) { ws[0] = 0.f; ws[1] = (float)v; }
        }
    }
}

__global__ __launch_bounds__(256, 2) void cnce_main(
        const float* __restrict__ c, const float* __restrict__ z,
        const unsigned short* __restrict__ WT,
        const unsigned short* __restrict__ zbf,   // may be null (ws too small)
        const int* __restrict__ neg_shift,
        const int* __restrict__ length, float* __restrict__ ws) {
    // XCD swizzle: hw-block h -> work; XCD k gets 4 consecutive b (zbf slice L2-fits)
    const int h = blockIdx.x;
    const int work = ((h & 7) << 6) | (h >> 3);
    const int b  = work >> 4;
    const int l0 = (work & 15) * TL_;
    const int tid  = threadIdx.x;
    const int w    = tid >> 6;
    const int lane = tid & 63;
    const int hi   = lane >> 4;
    const int m    = lane & 15;

    // [0,32768): c-tile bf16 [64][256] swizzled
    // [32768,65536): Wc bf16 [64 l][256 d] swizzled (row-major, l-major)
    __shared__ char smem[65536];
    char* wcb = smem + 32768;

    // ---- stage c tile once ----
    {
        const float4* csrc = (const float4*)(c + (size_t)(b * L_ + l0) * CD_);
        #pragma unroll
        for (int it = 0; it < 16; ++it) {
            int fi = tid + it * 256;
            int l  = fi >> 6;
            int k4 = fi & 63;
            float4 v = csrc[fi];
            unsigned short hh[4] = { f2b(v.x), f2b(v.y), f2b(v.z), f2b(v.w) };
            int byte = (l * 512 + k4 * 8) ^ ((l & 15) << 4);
            *(uint2*)(smem + byte) = *(const uint2*)hh;
        }
    }
    __syncthreads();

    const int len_b = length[b];
    const bool owner = (hi == (m >> 2));      // diag owner: lane=(n>>2)*16+n, reg n&3
    const int  rsel  = m & 3;
    const int  gl    = l0 + w * 16 + m;
    const bool contrib = owner && (gl < len_b);
    int s_arr[NS_ - 1];
    #pragma unroll
    for (int j = 0; j < NS_ - 1; ++j) s_arr[j] = neg_shift[j];

    const unsigned short* zbb = zbf ? zbf + (size_t)b * L_ * ZD_ : nullptr;
    const float* zbF = z + (size_t)b * L_ * ZD_;

    float lsum = 0.f;

    for (int p = 0; p < P_; ++p) {
        // ---- GEMM (operand-swapped): acc[mi][ni] = WT-rows x c-rows ----
        // C'[d][l]: col = l = ni*16+(lane&15); row = d = w*64+mi*16+(lane>>4)*4+r
        f32x4 acc[4][4];
        #pragma unroll
        for (int mi = 0; mi < 4; ++mi)
            #pragma unroll
            for (int ni = 0; ni < 4; ++ni) acc[mi][ni] = (f32x4){0.f, 0.f, 0.f, 0.f};
        const unsigned short* WTp = WT + (size_t)p * ZD_ * CD_;
        #pragma unroll
        for (int kk = 0; kk < 8; ++kk) {
            bf16x8 wf[4], cfk[4];
            const int k0 = kk * 32 + hi * 8;
            #pragma unroll
            for (int mi = 0; mi < 4; ++mi) {
                int d = w * 64 + mi * 16 + m;
                wf[mi] = *(const bf16x8*)(WTp + (size_t)d * CD_ + k0);
            }
            #pragma unroll
            for (int ni = 0; ni < 4; ++ni) {
                int l = ni * 16 + m;
                int byte = (l * 512 + k0 * 2) ^ ((l & 15) << 4);
                cfk[ni] = *(const bf16x8*)(smem + byte);
            }
            #pragma unroll
            for (int mi = 0; mi < 4; ++mi)
                #pragma unroll
                for (int ni = 0; ni < 4; ++ni)
                    acc[mi][ni] = __builtin_amdgcn_mfma_f32_16x16x32_bf16(
                        wf[mi], cfk[ni], acc[mi][ni], 0, 0, 0);
        }
        __syncthreads();   // all waves done reading previous p's Wc
        // ---- spill Wc: lane holds (l fixed, 4 consecutive d) -> packed b64 ----
        #pragma unroll
        for (int mi = 0; mi < 4; ++mi)
            #pragma unroll
            for (int ni = 0; ni < 4; ++ni) {
                int l  = ni * 16 + m;
                int d0 = w * 64 + mi * 16 + hi * 4;
                unsigned short hh[4] = { f2b(acc[mi][ni][0]), f2b(acc[mi][ni][1]),
                                         f2b(acc[mi][ni][2]), f2b(acc[mi][ni][3]) };
                int byte = (l * 512 + d0 * 2) ^ ((l & 15) << 4);
                *(uint2*)(wcb + byte) = *(const uint2*)hh;
            }
        __syncthreads();
        // ---- phase B: diag-MFMA scores; wave w owns rows [w*16, w*16+16) ----
        bf16x8 pav[8];
        #pragma unroll
        for (int kk = 0; kk < 8; ++kk) {
            int l  = w * 16 + m;
            int k0 = kk * 32 + hi * 8;
            int byte = (l * 512 + k0 * 2) ^ ((l & 15) << 4);
            pav[kk] = *(const bf16x8*)(wcb + byte);
        }
        float scores[NS_];
        #pragma unroll
        for (int j = 0; j < NS_; ++j) {
            const int s = (j == 0) ? (p + 1) : s_arr[j - 1];
            const int rowz = (l0 + w * 16 + m + s) & (L_ - 1);
            f32x4 e = {0.f, 0.f, 0.f, 0.f}, o = {0.f, 0.f, 0.f, 0.f};
            if (zbb) {
                const unsigned short* zr = zbb + (size_t)rowz * ZD_ + hi * 8;
                #pragma unroll
                for (int kk = 0; kk < 8; kk += 2) {
                    bf16x8 b0 = *(const bf16x8*)(zr + kk * 32);
                    bf16x8 b1 = *(const bf16x8*)(zr + kk * 32 + 32);
                    e = __builtin_amdgcn_mfma_f32_16x16x32_bf16(pav[kk],     b0, e, 0, 0, 0);
                    o = __builtin_amdgcn_mfma_f32_16x16x32_bf16(pav[kk + 1], b1, o, 0, 0, 0);
                }
            } else {
                const float* zr = zbF + (size_t)rowz * ZD_ + hi * 8;
                #pragma unroll
                for (int kk = 0; kk < 8; ++kk) {
                    float4 z0 = *(const float4*)(zr + kk * 32);
                    float4 z1 = *(const float4*)(zr + kk * 32 + 4);
                    unsigned short hh[8] = { f2b(z0.x), f2b(z0.y), f2b(z0.z), f2b(z0.w),
                                             f2b(z1.x), f2b(z1.y), f2b(z1.z), f2b(z1.w) };
                    bf16x8 bz = *(const bf16x8*)hh;
                    if (kk & 1) o = __builtin_amdgcn_mfma_f32_16x16x32_bf16(pav[kk], bz, o, 0, 0, 0);
                    else        e = __builtin_amdgcn_mfma_f32_16x16x32_bf16(pav[kk], bz, e, 0, 0, 0);
                }
            }
            scores[j] = (rsel == 0) ? e[0] + o[0] : (rsel == 1) ? e[1] + o[1]
                      : (rsel == 2) ? e[2] + o[2] : e[3] + o[3];
        }
        if (contrib) {
            float mx = scores[0];
            #pragma unroll
            for (int j = 1; j < NS_; ++j) mx = fmaxf(mx, scores[j]);
            float se = 0.f;
            #pragma unroll
            for (int j = 0; j < NS_; ++j) se += __expf(scores[j] - mx);
            lsum += __logf(se) + mx - scores[0];
        }
    }
    #pragma unroll
    for (int sh = 1; sh < 64; sh <<= 1) lsum += __shfl_xor(lsum, sh);
    if (lane == 0) atomicAdd(&ws[0], lsum);
}

__global__ void cnce_fin(const float* __restrict__ ws, float* __restrict__ out) {
    out[0] = ws[0] / ws[1];
}

extern "C" void kernel_launch(void* const* d_in, const int* in_sizes, int n_in,
                              void* d_out, int out_size, void* d_ws, size_t ws_size,
                              hipStream_t stream) {
    const float* c  = (const float*)d_in[0];
    const float* z  = (const float*)d_in[1];
    const float* W  = (const float*)d_in[2];
    const int* neg_shift = (const int*)d_in[3];
    const int* length    = (const int*)d_in[4];
    float* out = (float*)d_out;
    float* ws  = (float*)d_ws;
    unsigned short* WT = (unsigned short*)((char*)d_ws + 256);

    const size_t ZBF_OFF = 256 + (size_t)P_ * CD_ * ZD_ * 2;          // 1,573,120
    const size_t NEED    = ZBF_OFF + (size_t)B_ * L_ * ZD_ * 2;       // ~18.35 MB
    unsigned short* zbf = (ws_size >= NEED)
                        ? (unsigned short*)((char*)d_ws + ZBF_OFF) : nullptr;

    cnce_prep<<<4481, 256, 0, stream>>>(W, WT, z, zbf, length, ws);
    cnce_main<<<512, 256, 0, stream>>>(c, z, WT, zbf, neg_shift, length, ws);
    cnce_fin<<<1, 1, 0, stream>>>(ws, out);
}